// Round 1
// baseline (3379.973 us; speedup 1.0000x reference)
//
#include <hip/hip_runtime.h>
#include <math.h>

#define B_TOK 128
#define HDIM  2048
#define NEXP  64
#define IDIM  768
#define TOPK  8
#define TB    32      // token tile
#define KB    32      // k tile (floats)

struct WS {
  int   counts[NEXP];
  int   tok_pair[NEXP][B_TOK];   // pair id = b*TOPK + slot
  float tok_wt[NEXP][B_TOK];     // renormalized routing weight
  float inter[B_TOK * TOPK][IDIM];
  float out_slots[B_TOK * TOPK][HDIM];
};

// ---------------------------------------------------------------- gating ----
__global__ __launch_bounds__(256) void gate_kernel(const float* __restrict__ x,
                                                   const float* __restrict__ gw,
                                                   WS* __restrict__ ws) {
  const int b    = blockIdx.x;
  const int e    = threadIdx.x & 63;
  const int part = threadIdx.x >> 6;   // 0..3, splits H
  const float* xr = x + (size_t)b * HDIM;
  const float* gr = gw + (size_t)e * HDIM;
  float acc = 0.f;
  const int h0 = part * (HDIM / 4);
  for (int h = h0; h < h0 + HDIM / 4; h += 4) {
    float4 xv = *(const float4*)(xr + h);
    float4 gv = *(const float4*)(gr + h);
    acc += xv.x * gv.x + xv.y * gv.y + xv.z * gv.z + xv.w * gv.w;
  }
  __shared__ float partial[4][NEXP];
  partial[part][e] = acc;
  __syncthreads();
  if (threadIdx.x < NEXP) {
    partial[0][e] = partial[0][e] + partial[1][e] + partial[2][e] + partial[3][e];
  }
  __syncthreads();
  if (threadIdx.x == 0) {
    float* logits = partial[0];
    unsigned long long mask = 0;
    int   idx[TOPK];
    float val[TOPK];
    for (int s = 0; s < TOPK; ++s) {
      float best = -3.4e38f; int bi = 0;
      for (int j = 0; j < NEXP; ++j) {
        if (!((mask >> j) & 1ull) && logits[j] > best) { best = logits[j]; bi = j; }
      }
      mask |= 1ull << bi; idx[s] = bi; val[s] = best;
    }
    // softmax over top-8 (== topk(softmax)/sum(topk))
    float mx = val[0], denom = 0.f, w[TOPK];
    for (int s = 0; s < TOPK; ++s) { w[s] = expf(val[s] - mx); denom += w[s]; }
    float inv = 1.f / denom;
    for (int s = 0; s < TOPK; ++s) {
      int ee  = idx[s];
      int pos = atomicAdd(&ws->counts[ee], 1);
      ws->tok_pair[ee][pos] = b * TOPK + s;
      ws->tok_wt[ee][pos]   = w[s] * inv;
    }
  }
}

// --------------------------------------------------------------- ffn1 -------
// per block: expert e, i-chunk of 64. Rows 0..63 = gate rows i0+r,
// rows 64..127 = up rows IDIM+i0+r. Computes inter = silu(g)*u.
__global__ __launch_bounds__(256, 4) void ffn1_kernel(const float* __restrict__ x,
                                                      const float* __restrict__ w1,
                                                      WS* __restrict__ ws) {
  const int e  = blockIdx.x;
  const int i0 = blockIdx.y * 64;
  const int nt = ws->counts[e];
  if (nt == 0) return;

  __shared__ float wt_tile[128][36];   // stride 36: b128 reads hit all 32 banks evenly
  __shared__ float x_tile[TB][KB];     // broadcast reads, no pad needed
  __shared__ int   spair[TB];

  const int tid = threadIdx.x;
  const int r   = tid & 63;           // row within 0..63
  const int tg  = tid >> 6;           // token group 0..3 (8 tokens each)

  // W staging map: 2 threads per row, each loads 64 contiguous bytes
  const int srow  = tid >> 1;         // 0..127
  const int shalf = tid & 1;
  const int grow  = (srow < 64) ? (i0 + srow) : (IDIM + i0 + (srow - 64));
  const float* wrow = w1 + ((size_t)e * (2 * IDIM) + grow) * HDIM + shalf * 16;

  for (int t0 = 0; t0 < nt; t0 += TB) {
    if (tid < TB) {
      int t = t0 + tid;
      spair[tid] = (t < nt) ? ws->tok_pair[e][t] : -1;
    }
    __syncthreads();

    // x staging map: 4 threads per token (threads 0..127)
    const float* xrow = nullptr;
    if (tid < 128) {
      int xt = tid >> 2, xq = tid & 3;
      int p  = spair[xt];
      int bb = (p < 0) ? 0 : (p >> 3);
      xrow = x + (size_t)bb * HDIM + xq * 4;
    }

    float ag[8] = {0, 0, 0, 0, 0, 0, 0, 0};
    float au[8] = {0, 0, 0, 0, 0, 0, 0, 0};

    for (int kk = 0; kk < HDIM; kk += KB) {
      float4 wv0 = *(const float4*)(wrow + kk);
      float4 wv1 = *(const float4*)(wrow + kk + 4);
      float4 wv2 = *(const float4*)(wrow + kk + 8);
      float4 wv3 = *(const float4*)(wrow + kk + 12);
      float4 xv0 = {0, 0, 0, 0}, xv1 = {0, 0, 0, 0};
      if (tid < 128) {
        xv0 = *(const float4*)(xrow + kk);
        xv1 = *(const float4*)(xrow + kk + 16);
      }
      __syncthreads();   // previous tile fully consumed
      {
        float* wd = &wt_tile[srow][shalf * 16];
        *(float4*)(wd + 0)  = wv0;
        *(float4*)(wd + 4)  = wv1;
        *(float4*)(wd + 8)  = wv2;
        *(float4*)(wd + 12) = wv3;
        if (tid < 128) {
          int xt = tid >> 2, xq = tid & 3;
          *(float4*)&x_tile[xt][xq * 4]      = xv0;
          *(float4*)&x_tile[xt][xq * 4 + 16] = xv1;
        }
      }
      __syncthreads();   // tile ready
#pragma unroll
      for (int k = 0; k < KB; k += 4) {
        float4 wg = *(const float4*)&wt_tile[r][k];
        float4 wu = *(const float4*)&wt_tile[64 + r][k];
#pragma unroll
        for (int tt = 0; tt < 8; ++tt) {
          float4 xv = *(const float4*)&x_tile[tg * 8 + tt][k];
          ag[tt] += wg.x * xv.x + wg.y * xv.y + wg.z * xv.z + wg.w * xv.w;
          au[tt] += wu.x * xv.x + wu.y * xv.y + wu.z * xv.z + wu.w * xv.w;
        }
      }
    }

    // epilogue: silu(gate)*up -> inter[pair][i0+r]
#pragma unroll
    for (int tt = 0; tt < 8; ++tt) {
      int t = t0 + tg * 8 + tt;
      if (t < nt) {
        int   p = spair[tg * 8 + tt];
        float g = ag[tt], u = au[tt];
        float sv = g / (1.f + expf(-g));
        ws->inter[p][i0 + r] = sv * u;
      }
    }
    __syncthreads();     // spair reads done before next chunk overwrites
  }
}

// --------------------------------------------------------------- ffn2 -------
// per block: expert e, h-chunk of 128. out_slots[pair][h] = wt * (inter . w2[e,h,:])
__global__ __launch_bounds__(256, 4) void ffn2_kernel(const float* __restrict__ w2,
                                                      WS* __restrict__ ws) {
  const int e  = blockIdx.x;
  const int h0 = blockIdx.y * 128;
  const int nt = ws->counts[e];
  if (nt == 0) return;

  __shared__ float wt_tile[128][36];
  __shared__ float v_tile[TB][KB];
  __shared__ int   spair[TB];
  __shared__ float swt[TB];

  const int tid = threadIdx.x;
  const int r   = tid & 63;
  const int tg  = tid >> 6;

  const int srow  = tid >> 1;
  const int shalf = tid & 1;
  const float* wrow = w2 + ((size_t)e * HDIM + h0 + srow) * IDIM + shalf * 16;

  for (int t0 = 0; t0 < nt; t0 += TB) {
    if (tid < TB) {
      int t = t0 + tid;
      int p = (t < nt) ? ws->tok_pair[e][t] : -1;
      spair[tid] = p;
      swt[tid]   = (t < nt) ? ws->tok_wt[e][t] : 0.f;
    }
    __syncthreads();

    const float* vrow = nullptr;
    if (tid < 128) {
      int xt = tid >> 2, xq = tid & 3;
      int p  = spair[xt];
      int pp = (p < 0) ? 0 : p;
      vrow = &ws->inter[pp][0] + xq * 4;
    }

    float a0[8] = {0, 0, 0, 0, 0, 0, 0, 0};
    float a1[8] = {0, 0, 0, 0, 0, 0, 0, 0};

    for (int kk = 0; kk < IDIM; kk += KB) {
      float4 wv0 = *(const float4*)(wrow + kk);
      float4 wv1 = *(const float4*)(wrow + kk + 4);
      float4 wv2 = *(const float4*)(wrow + kk + 8);
      float4 wv3 = *(const float4*)(wrow + kk + 12);
      float4 xv0 = {0, 0, 0, 0}, xv1 = {0, 0, 0, 0};
      if (tid < 128) {
        xv0 = *(const float4*)(vrow + kk);
        xv1 = *(const float4*)(vrow + kk + 16);
      }
      __syncthreads();
      {
        float* wd = &wt_tile[srow][shalf * 16];
        *(float4*)(wd + 0)  = wv0;
        *(float4*)(wd + 4)  = wv1;
        *(float4*)(wd + 8)  = wv2;
        *(float4*)(wd + 12) = wv3;
        if (tid < 128) {
          int xt = tid >> 2, xq = tid & 3;
          *(float4*)&v_tile[xt][xq * 4]      = xv0;
          *(float4*)&v_tile[xt][xq * 4 + 16] = xv1;
        }
      }
      __syncthreads();
#pragma unroll
      for (int k = 0; k < KB; k += 4) {
        float4 w0 = *(const float4*)&wt_tile[r][k];
        float4 w1v = *(const float4*)&wt_tile[64 + r][k];
#pragma unroll
        for (int tt = 0; tt < 8; ++tt) {
          float4 xv = *(const float4*)&v_tile[tg * 8 + tt][k];
          a0[tt] += w0.x * xv.x + w0.y * xv.y + w0.z * xv.z + w0.w * xv.w;
          a1[tt] += w1v.x * xv.x + w1v.y * xv.y + w1v.z * xv.z + w1v.w * xv.w;
        }
      }
    }

#pragma unroll
    for (int tt = 0; tt < 8; ++tt) {
      int t = t0 + tg * 8 + tt;
      if (t < nt) {
        int   p  = spair[tg * 8 + tt];
        float wt = swt[tg * 8 + tt];
        ws->out_slots[p][h0 + r]      = wt * a0[tt];
        ws->out_slots[p][h0 + 64 + r] = wt * a1[tt];
      }
    }
    __syncthreads();
  }
}

// -------------------------------------------------------------- reduce ------
__global__ __launch_bounds__(256) void reduce_kernel(const WS* __restrict__ ws,
                                                     float* __restrict__ out) {
  int gid = blockIdx.x * 256 + threadIdx.x;   // B_TOK * HDIM / 4 threads
  int b   = gid >> 9;                          // HDIM/4 = 512 float4 per token
  int h4  = (gid & 511) * 4;
  float4 s = {0, 0, 0, 0};
#pragma unroll
  for (int sl = 0; sl < TOPK; ++sl) {
    float4 v = *(const float4*)&ws->out_slots[b * TOPK + sl][h4];
    s.x += v.x; s.y += v.y; s.z += v.z; s.w += v.w;
  }
  *(float4*)(out + (size_t)b * HDIM + h4) = s;
}

// -------------------------------------------------------------- launch ------
extern "C" void kernel_launch(void* const* d_in, const int* in_sizes, int n_in,
                              void* d_out, int out_size, void* d_ws, size_t ws_size,
                              hipStream_t stream) {
  (void)in_sizes; (void)n_in; (void)out_size; (void)ws_size;
  const float* x  = (const float*)d_in[0];
  const float* gw = (const float*)d_in[1];
  const float* w1 = (const float*)d_in[2];
  const float* w2 = (const float*)d_in[3];
  WS* ws = (WS*)d_ws;

  hipMemsetAsync(ws->counts, 0, sizeof(int) * NEXP, stream);
  gate_kernel<<<B_TOK, 256, 0, stream>>>(x, gw, ws);
  ffn1_kernel<<<dim3(NEXP, IDIM / 64), 256, 0, stream>>>(x, w1, ws);
  ffn2_kernel<<<dim3(NEXP, HDIM / 128), 256, 0, stream>>>(w2, ws);
  reduce_kernel<<<(B_TOK * HDIM / 4) / 256, 256, 0, stream>>>(ws, (float*)d_out);
}